// Round 4
// baseline (476.915 us; speedup 1.0000x reference)
//
#include <hip/hip_runtime.h>
#include <hip/hip_bf16.h>

// Problem dims
#define B_  32
#define C_  16
#define Hh  64
#define Ww  64
#define O_  256
#define Kk  5
#define Ho_ 60
#define Wo_ 60
#define Dd  400                 // C*K*K
#define Nn  (B_*Ho_*Wo_)        // 115200
#define NY  ((size_t)B_*O_*Ho_*Wo_)  // 29491200

typedef float f4 __attribute__((ext_vector_type(4)));

// ---------------- prep: transpose w [O][D] -> wT [D][O], zero counts ----------------
__global__ void prep_kernel(const float* __restrict__ w, float* __restrict__ wT,
                            int* __restrict__ count) {
    int k = blockIdx.x;              // 0..399
    int o = threadIdx.x;             // 0..255
    wT[k * O_ + o] = w[o * Dd + k];
    if (blockIdx.x == 0) count[o] = 0;
}

// ---------------- phase 1: fp32 conv + per-row argmax + winner append + fp32 y ----------
// grid = 32*60 blocks (one per (b,ho)), 256 threads.
// lane txo=tid&63 owns o = txo + 64u (u=0..3); wave ty=tid>>6 owns wo in [16*ty, 16*ty+16)
__launch_bounds__(256, 3)
__global__ void conv_argmax_kernel(const float* __restrict__ x, const float* __restrict__ wT,
                                   float* __restrict__ y, int* __restrict__ count,
                                   int* __restrict__ lw_n, float* __restrict__ lw_s,
                                   int cap) {
    __shared__ float xs[C_][Kk][68];     // 21,760 B  x patch rows, cols 0..63 + zero pad
    __shared__ float ws[25][O_];         // 25,600 B  one channel-chunk of wT

    const int tid = threadIdx.x;
    const int txo = tid & 63;
    const int ty  = tid >> 6;            // wave id, 0..3
    const int b   = blockIdx.x / Ho_;
    const int ho  = blockIdx.x % Ho_;
    const int wo0 = ty * 16;

    // ---- stage x patch: x[b, c, ho+i, 0..63] for c=0..15, i=0..4 (80 rows of 64 floats)
    {
        const float* xb = x + (size_t)b * (C_ * Hh * Ww);
        for (int idx = tid; idx < 80 * 16; idx += 256) {
            int row  = idx >> 4;          // 0..79
            int col4 = idx & 15;
            int c = row / 5, i = row % 5;
            const f4* src = reinterpret_cast<const f4*>(xb + (c * Hh + (ho + i)) * Ww) + col4;
            *reinterpret_cast<f4*>(&xs[c][i][col4 * 4]) = *src;
        }
        if (tid < 80) {
            int c = tid / 5, i = tid % 5;
            xs[c][i][64] = 0.f; xs[c][i][65] = 0.f; xs[c][i][66] = 0.f; xs[c][i][67] = 0.f;
        }
    }

    float acc[16][4];
    #pragma unroll
    for (int r = 0; r < 16; ++r) {
        acc[r][0] = 0.f; acc[r][1] = 0.f; acc[r][2] = 0.f; acc[r][3] = 0.f;
    }

    // ---- main loop over channels; stage wT chunk [25][256] per channel
    #pragma unroll 1
    for (int c = 0; c < C_; ++c) {
        __syncthreads();   // prior chunk's reads done (first iter: xs staging done)
        {
            const f4* srcb = reinterpret_cast<const f4*>(wT + c * 25 * O_);
            f4* dstb = reinterpret_cast<f4*>(&ws[0][0]);
            #pragma unroll
            for (int t = 0; t < 6; ++t) dstb[tid + t * 256] = srcb[tid + t * 256];
            if (tid < 64) dstb[tid + 1536] = srcb[tid + 1536];
        }
        __syncthreads();

        #pragma unroll 1
        for (int i = 0; i < Kk; ++i) {
            float seg[20];                 // xs[c][i][wo0 .. wo0+19], wave-uniform broadcast
            #pragma unroll
            for (int t = 0; t < 20; ++t) seg[t] = xs[c][i][wo0 + t];
            #pragma unroll
            for (int j = 0; j < Kk; ++j) {
                float bb[4];
                #pragma unroll
                for (int u = 0; u < 4; ++u) bb[u] = ws[i * 5 + j][txo + 64 * u];
                #pragma unroll
                for (int r = 0; r < 16; ++r) {
                    const float a = seg[r + j];
                    #pragma unroll
                    for (int u = 0; u < 4; ++u) acc[r][u] = fmaf(a, bb[u], acc[r][u]);
                }
            }
        }
    }

    // ---- per-row argmax over all 256 o (exact tie handling like s == s.max())
    #pragma unroll
    for (int r = 0; r < 16; ++r) {
        const int wo = wo0 + r;
        float v = fmaxf(fmaxf(acc[r][0], acc[r][1]), fmaxf(acc[r][2], acc[r][3]));
        #pragma unroll
        for (int off = 32; off >= 1; off >>= 1) v = fmaxf(v, __shfl_xor(v, off));
        if (wo < Wo_) {
            const int n = (b * Ho_ + ho) * Wo_ + wo;
            #pragma unroll
            for (int u = 0; u < 4; ++u) {
                if (acc[r][u] == v) {                     // winner (possibly tied)
                    const int o = txo + 64 * u;
                    int pos = atomicAdd(&count[o], 1);
                    if (pos < cap) { lw_n[o * cap + pos] = n; lw_s[o * cap + pos] = v; }
                }
            }
        }
    }

    // ---- y stores: fp32, each lane owns 16 consecutive wo -> float4 stores
    {
        const int nf4 = (Wo_ - wo0) / 4 < 4 ? (Wo_ - wo0) / 4 : 4;   // wo0=48 -> 3, else 4
        #pragma unroll
        for (int u = 0; u < 4; ++u) {
            const int o = txo + 64 * u;
            float* row = y + ((size_t)(b * O_ + o) * Ho_ + ho) * (size_t)Wo_ + wo0;
            #pragma unroll
            for (int q = 0; q < 4; ++q) {
                if (q < nf4) {
                    f4 v4 = { acc[q * 4 + 0][u], acc[q * 4 + 1][u],
                              acc[q * 4 + 2][u], acc[q * 4 + 3][u] };
                    *reinterpret_cast<f4*>(row + q * 4) = v4;
                }
            }
        }
    }
}

// ---------------- phase 2: delta_w[o,d] = (1/N)*sum_win s*x_unf[n,d] - (sum_win s/N)*w[o,d]
// grid = 256 blocks (one per o), 256 threads (thread -> d and d+256)
__global__ void delta_kernel(const float* __restrict__ x, const float* __restrict__ w,
                             const int* __restrict__ count, const int* __restrict__ lw_n,
                             const float* __restrict__ lw_s, float* __restrict__ dout,
                             int cap) {
    const int o   = blockIdx.x;
    const int tid = threadIdx.x;
    int cnt = count[o]; if (cnt > cap) cnt = cap;

    const int d0 = tid;
    const int c0 = d0 / 25, r0 = d0 % 25, i0 = r0 / 5, j0 = r0 % 5;
    const int d1 = tid + 256;
    const bool has1 = (d1 < Dd);
    const int dd1 = has1 ? d1 : 0;
    const int c1 = dd1 / 25, r1 = dd1 % 25, i1 = r1 / 5, j1 = r1 % 5;

    const int* ln = lw_n + (size_t)o * cap;
    const float* ls = lw_s + (size_t)o * cap;

    float acc0 = 0.f, acc1 = 0.f, ssum = 0.f;
    #pragma unroll 4
    for (int e = 0; e < cnt; ++e) {
        const int n = ln[e];
        const float s = ls[e];
        const int bb = n / 3600;
        const int rem = n - bb * 3600;
        const int hh = rem / 60;
        const int ww2 = rem - hh * 60;
        ssum += s;
        const float* xb = x + (size_t)bb * (C_ * Hh * Ww);
        acc0 += s * xb[(c0 * Hh + hh + i0) * Ww + ww2 + j0];
        if (has1) acc1 += s * xb[(c1 * Hh + hh + i1) * Ww + ww2 + j1];
    }

    const float invN = 1.0f / (float)Nn;
    dout[NY + (size_t)o * Dd + d0] = acc0 * invN - ssum * invN * w[o * Dd + d0];
    if (has1)
        dout[NY + (size_t)o * Dd + d1] = acc1 * invN - ssum * invN * w[o * Dd + d1];
}

extern "C" void kernel_launch(void* const* d_in, const int* in_sizes, int n_in,
                              void* d_out, int out_size, void* d_ws, size_t ws_size,
                              hipStream_t stream) {
    (void)in_sizes; (void)n_in; (void)out_size;
    const float* x = (const float*)d_in[0];
    const float* w = (const float*)d_in[1];
    float* out = (float*)d_out;

    char* ws = (char*)d_ws;
    int*   count = (int*)ws;                       // 1 KB
    float* wT    = (float*)(ws + 1024);            // 400 KB, 16B-aligned
    const size_t base = 1024 + (size_t)Dd * O_ * 4;   // 410,624 B

    // size winner lists from the actual workspace; never write beyond it
    size_t avail = (ws_size > base) ? (ws_size - base) : 0;
    long long cap_ll = (long long)(avail / ((size_t)O_ * 8));
    int cap = (int)(cap_ll > 4096 ? 4096 : (cap_ll < 1 ? 1 : cap_ll));

    int*   lw_n = (int*)(ws + base);
    float* lw_s = (float*)(ws + base + (size_t)O_ * cap * 4);

    prep_kernel<<<dim3(Dd), dim3(O_), 0, stream>>>(w, wT, count);
    conv_argmax_kernel<<<dim3(B_ * Ho_), dim3(256), 0, stream>>>(x, wT, out, count, lw_n, lw_s, cap);
    delta_kernel<<<dim3(O_), dim3(256), 0, stream>>>(x, w, count, lw_n, lw_s, out, cap);
}